// Round 13
// baseline (1201.925 us; speedup 1.0000x reference)
//
#include <hip/hip_runtime.h>
#include <math.h>

#define BATCH 256
#define LEN   10000
#define C0 64
#define P0 624
#define T1 155
#define P1 77

// ws offsets (in floats)
#define OFF_CONST 0
#define OFF_BAR   160        // barrier slot lines: 8 groups x 32 members x 64B = 16KB
#define OFF_Y1    2560160
#define OFF_X     12783776
#define OFF_H0    15306912
#define OFF_C0    15437984
#define OFF_H1    15503520
#define OFF_C1    15634592
#define OFF_Z0    15700128
#define OFF_Z1    15831200
#define OFF_TMP   15962272

// ---------------- host-side savgol constants ----------------
static void invert4(const double A[4][4], double inv[4][4]) {
  double M[4][8];
  for (int i = 0; i < 4; ++i)
    for (int j = 0; j < 4; ++j) { M[i][j] = A[i][j]; M[i][j+4] = (i==j) ? 1.0 : 0.0; }
  for (int col = 0; col < 4; ++col) {
    int p = col;
    for (int r = col+1; r < 4; ++r) if (fabs(M[r][col]) > fabs(M[p][col])) p = r;
    if (p != col) for (int j = 0; j < 8; ++j) { double t = M[col][j]; M[col][j] = M[p][j]; M[p][j] = t; }
    double d = M[col][col];
    for (int j = 0; j < 8; ++j) M[col][j] /= d;
    for (int r = 0; r < 4; ++r) if (r != col) {
      double f = M[r][col];
      for (int j = 0; j < 8; ++j) M[r][j] -= f * M[col][j];
    }
  }
  for (int i = 0; i < 4; ++i) for (int j = 0; j < 4; ++j) inv[i][j] = M[i][j+4];
}

static void compute_consts(float* out) {
  {
    double V[11][4], A[4][4], inv[4][4];
    for (int w = 0; w < 11; ++w) { double t = (double)(w-5), pw = 1.0; for (int m = 0; m < 4; ++m) { V[w][m] = pw; pw *= t; } }
    for (int m = 0; m < 4; ++m) for (int n = 0; n < 4; ++n) { double s = 0; for (int w = 0; w < 11; ++w) s += V[w][m]*V[w][n]; A[m][n] = s; }
    invert4(A, inv);
    for (int w = 0; w < 11; ++w) { double s = 0; for (int m = 0; m < 4; ++m) s += inv[0][m]*V[w][m]; out[w] = (float)s; }
  }
  {
    double V[11][4], A[4][4], inv[4][4], pe[4][11];
    for (int w = 0; w < 11; ++w) { double t = (double)w, pw = 1.0; for (int m = 0; m < 4; ++m) { V[w][m] = pw; pw *= t; } }
    for (int m = 0; m < 4; ++m) for (int n = 0; n < 4; ++n) { double s = 0; for (int w = 0; w < 11; ++w) s += V[w][m]*V[w][n]; A[m][n] = s; }
    invert4(A, inv);
    for (int m = 0; m < 4; ++m) for (int w = 0; w < 11; ++w) { double s = 0; for (int n = 0; n < 4; ++n) s += inv[m][n]*V[w][n]; pe[m][w] = s; }
    for (int w = 0; w < 11; ++w) for (int k = 0; k < 5; ++k) {
      double s = 0, pk = 1.0;
      for (int m = 0; m < 4; ++m) { s += pe[m][w]*pk; pk *= (double)k; }
      out[16 + w*5 + k] = (float)s;
    }
    for (int w = 0; w < 11; ++w) for (int k = 0; k < 5; ++k) {
      double tv = (double)(6+k), s = 0, pk = 1.0;
      for (int m = 0; m < 4; ++m) { s += pe[m][w]*pk; pk *= tv; }
      out[80 + w*5 + k] = (float)s;
    }
  }
}

// ---------------- fused savgol + conv0 + relu + pool2 + bn: x -> y1 (256,64,624) ----------------
__global__ __launch_bounds__(256) void k_sgconv0(const float* __restrict__ x,
    const float* __restrict__ Cc,
    const float* __restrict__ w0, const float* __restrict__ cb0,
    const float* __restrict__ bg0, const float* __restrict__ bb0,
    const float* __restrict__ bm0, const float* __restrict__ bv0,
    float* __restrict__ y1) {
  __shared__ float sw[1024];
  __shared__ float s_sc[64], s_off[64], s_cb[64];
  int tid = threadIdx.x;
  for (int i = tid; i < 1024; i += 256) sw[i] = w0[i];
  if (tid < 64) {
    float sc = bg0[tid] * rsqrtf(bv0[tid] + 1e-5f);
    s_sc[tid] = sc;
    s_off[tid] = bb0[tid] - bm0[tid]*sc;
    s_cb[tid] = cb0[tid];
  }
  __syncthreads();
  int b = blockIdx.y;
  int uu = blockIdx.x*256 + tid;
  if (uu >= P0) return;
  const float* xb = x + b*LEN;
  float hC[11];
#pragma unroll
  for (int w = 0; w < 11; ++w) hC[w] = Cc[w];
  float iv[24];
  if (uu == 0) {
    float xx[32];
    const float4* p = reinterpret_cast<const float4*>(xb);
#pragma unroll
    for (int j = 0; j < 8; ++j) { float4 v = p[j]; xx[4*j]=v.x; xx[4*j+1]=v.y; xx[4*j+2]=v.z; xx[4*j+3]=v.w; }
#pragma unroll
    for (int j = 0; j < 24; ++j) {
      float s = 0.f;
      if (j < 5) {
        for (int w = 0; w < 11; ++w) s += xx[w] * Cc[16 + w*5 + j];
      } else {
        for (int w = 0; w < 11; ++w) s += xx[j-5+w] * hC[w];
      }
      iv[j] = s;
    }
  } else {
    float xx[40];
    const float4* p = reinterpret_cast<const float4*>(xb + 16*uu - 8);
#pragma unroll
    for (int j = 0; j < 10; ++j) { float4 v = p[j]; xx[4*j]=v.x; xx[4*j+1]=v.y; xx[4*j+2]=v.z; xx[4*j+3]=v.w; }
#pragma unroll
    for (int j = 0; j < 24; ++j) {
      float s = 0.f;
#pragma unroll
      for (int w = 0; w < 11; ++w) s += xx[j+3+w] * hC[w];
      iv[j] = s;
    }
  }
  int obase = b*(C0*P0) + uu;
  for (int oc = 0; oc < 64; ++oc) {
    float bias = s_cb[oc];
    float s0 = bias, s1 = bias;
#pragma unroll
    for (int k = 0; k < 16; ++k) {
      float wk = sw[oc*16 + k];
      s0 += iv[k]   * wk;
      s1 += iv[k+8] * wk;
    }
    float pm = fmaxf(fmaxf(s0, 0.f), fmaxf(s1, 0.f));
    y1[obase + oc*P0] = pm*s_sc[oc] + s_off[oc];
  }
}

// ---------------- conv1 as im2col GEMM: 64m x 128n tiles, K=512, 620 blocks ----------------
__global__ __launch_bounds__(256) void k_conv1_gemm(const float* __restrict__ y1,
    const float* __restrict__ w1, const float* __restrict__ cb1,
    float* __restrict__ tmp) {
  __shared__ __align__(16) float a_t[32*66];
  __shared__ __align__(16) float w_t[32*132];
  int m0 = blockIdx.x * 64;
  int tid = threadIdx.x;
  int sa_s = tid & 7, sa_r = tid >> 3;
  int un = tid & 31, mq = tid >> 5;
  int ybase[2];
#pragma unroll
  for (int i = 0; i < 2; ++i) {
    int m = m0 + sa_r + 32*i;
    int b = m / 155, t = m - b*155;
    ybase[i] = b*(C0*P0) + 4*t;
  }
  int ci_off = sa_s >> 1, kkq = (sa_s & 1) * 4;
  float4 av[2], wv[4];
  float acc[8][4] = {{0.f}};
  int swzw = sa_s << 2;

#define CONV1_PREFETCH(cidx) do {                                                   \
    int kc = (cidx) * 32;                                                           \
    int ci0 = kc >> 3;                                                              \
    av[0] = *reinterpret_cast<const float4*>(y1 + ybase[0] + (ci0 + ci_off)*P0 + kkq); \
    av[1] = *reinterpret_cast<const float4*>(y1 + ybase[1] + (ci0 + ci_off)*P0 + kkq); \
    _Pragma("unroll")                                                               \
    for (int i = 0; i < 4; ++i)                                                     \
      wv[i] = *reinterpret_cast<const float4*>(w1 + (sa_r + 32*i)*512 + kc + 4*sa_s); \
  } while (0)

  CONV1_PREFETCH(0);
  for (int cidx = 0; cidx < 16; ++cidx) {
    if (cidx) __syncthreads();
#pragma unroll
    for (int i = 0; i < 2; ++i) {
      int col = sa_r + 32*i;
      a_t[(4*sa_s+0)*66 + col] = av[i].x;
      a_t[(4*sa_s+1)*66 + col] = av[i].y;
      a_t[(4*sa_s+2)*66 + col] = av[i].z;
      a_t[(4*sa_s+3)*66 + col] = av[i].w;
    }
#pragma unroll
    for (int i = 0; i < 4; ++i) {
      int colw = (sa_r + 32*i) ^ swzw;
      w_t[(4*sa_s+0)*132 + colw] = wv[i].x;
      w_t[(4*sa_s+1)*132 + colw] = wv[i].y;
      w_t[(4*sa_s+2)*132 + colw] = wv[i].z;
      w_t[(4*sa_s+3)*132 + colw] = wv[i].w;
    }
    __syncthreads();
    if (cidx + 1 < 16) { CONV1_PREFETCH(cidx + 1); }
#pragma unroll
    for (int k = 0; k < 32; ++k) {
      float4 w4 = *reinterpret_cast<const float4*>(&w_t[k*132 + ((4*un) ^ ((k>>2)<<2))]);
      float2 a2[4];
#pragma unroll
      for (int i = 0; i < 4; ++i)
        a2[i] = *reinterpret_cast<const float2*>(&a_t[k*66 + 2*mq + 16*i]);
#pragma unroll
      for (int i = 0; i < 4; ++i) {
        acc[2*i+0][0] += a2[i].x*w4.x; acc[2*i+0][1] += a2[i].x*w4.y;
        acc[2*i+0][2] += a2[i].x*w4.z; acc[2*i+0][3] += a2[i].x*w4.w;
        acc[2*i+1][0] += a2[i].y*w4.x; acc[2*i+1][1] += a2[i].y*w4.y;
        acc[2*i+1][2] += a2[i].y*w4.z; acc[2*i+1][3] += a2[i].y*w4.w;
      }
    }
  }
#undef CONV1_PREFETCH
  float4 bias = *reinterpret_cast<const float4*>(cb1 + 4*un);
#pragma unroll
  for (int i = 0; i < 4; ++i)
#pragma unroll
    for (int jj = 0; jj < 2; ++jj) {
      int m = m0 + 2*mq + 16*i + jj;
      float4 o;
      o.x = acc[2*i+jj][0] + bias.x;
      o.y = acc[2*i+jj][1] + bias.y;
      o.z = acc[2*i+jj][2] + bias.z;
      o.w = acc[2*i+jj][3] + bias.w;
      *reinterpret_cast<float4*>(tmp + m*128 + 4*un) = o;
    }
}

// ---------------- relu + pool2 + bn: tmp -> X (77,256,128) t-major ----------------
__global__ __launch_bounds__(256) void k_pool1(const float* __restrict__ tmp,
    const float* __restrict__ bg1, const float* __restrict__ bb1,
    const float* __restrict__ bm1, const float* __restrict__ bv1,
    float* __restrict__ X) {
  int idx = blockIdx.x*256 + threadIdx.x;
  int u  = idx >> 15;
  int rr = idx & 32767;
  int bb = rr >> 7;
  int oc = rr & 127;
  int base = (bb*155 + 2*u)*128 + oc;
  float t0 = tmp[base], t1 = tmp[base + 128];
  float pm = fmaxf(0.f, fmaxf(t0, t1));
  float sc = bg1[oc] * rsqrtf(bv1[oc] + 1e-5f);
  X[idx] = pm*sc + (bb1[oc] - bm1[oc]*sc);
}

// ---- fence-free h exchange: relaxed AGENT-scope 8B atomics (sc1, bypass per-XCD L2,
// coherent at L3). Proven r11: removing the per-step fences cut persist 1628->984us. ----
__device__ __forceinline__ float2 h_load2(const float* p) {
  unsigned long long v = __hip_atomic_load((const unsigned long long*)p,
                                           __ATOMIC_RELAXED, __HIP_MEMORY_SCOPE_AGENT);
  float2 r;
  r.x = __uint_as_float((unsigned)v);
  r.y = __uint_as_float((unsigned)(v >> 32));
  return r;
}
__device__ __forceinline__ void h_store2(float* p, float a, float b) {
  unsigned long long v = (unsigned long long)__float_as_uint(a)
                       | ((unsigned long long)__float_as_uint(b) << 32);
  __hip_atomic_store((unsigned long long*)p, v,
                     __ATOMIC_RELAXED, __HIP_MEMORY_SCOPE_AGENT);
}

// ---------------- persistent LSTM v7b: V6 + LANE-MAJOR parallel reduction ----------------
// r11 (V6): 984us steady, conflicts 0. r12 (V7): 1020us, conflicts 5.68M -- the
// (4bq+bi)*64+8rq reduction layout mapped 64 lanes onto 4 banks (bq didn't move the
// bank at all); also single-buffered a_lds (second variable, WAR stall risk).
// v7b reverts to V6's dbuf/sleep(2) and changes ONLY the reduction, keeping the
// parallel 3-sync structure but with V6's PROVEN lane-major addressing
// (((qi<<6)+lane)<<2 -- 16B/lane sweep, zero conflicts):
//  sync1: w2 -> red[0:2048]  ||  w3 -> a_lds[0:2048]   (staging dead; parallel)
//  sync2: w0 += red || w1 += a_lds-scratch; give-away halves (w0 lanes>=32,
//         w1 lanes<32) write lane-major into a_lds[2048:4096] (disjoint lanes)
//  sync3: dual finishers -- w0 lanes<32 finish b0-15, w1 lanes>=32 finish b16-31;
//         activation + h-stores split over two waves/SIMDs. c_reg ownership is a
//         static (wave,lane) partition -> persists correctly across steps.
// LDS: W 128KB + A 16KB (dbuf) + red 8KB = 152KB. All else byte-identical to r11 V6.
__global__ __launch_bounds__(256) void k_lstm_persist(
    const float* __restrict__ X,
    const float* __restrict__ Wih0, const float* __restrict__ Whh0,
    const float* __restrict__ bih0, const float* __restrict__ bhh0,
    const float* __restrict__ Wih1, const float* __restrict__ Whh1,
    const float* __restrict__ bih1, const float* __restrict__ bhh1,
    float* __restrict__ h0buf, float* __restrict__ h1buf,
    unsigned* bar) {
  __shared__ __align__(16) float w_lds[512*64];   // [k][col], col = 4*ulocal + gate
  __shared__ __align__(16) float a_lds[4*2*16*32];// per-wave 2x [16k][32b] dbuf; red scratch
  __shared__ __align__(16) float red[2048];       // w2's reduction partial (8KB)

  const int blk  = blockIdx.x;
  const int g    = blk & 7;          // b-tile / barrier group
  const int role = blk >> 3;         // 0..31
  const int layer = role >> 4;
  const int u0   = (role & 15) * 16;
  const int b0   = g * 32;
  const int tid  = threadIdx.x;
  const int wv   = tid >> 6;
  const int lane = tid & 63;
  const int bq   = lane >> 3;        // batches b0 + 4*bq + {0..3}
  const int rq   = lane & 7;         // cols 8*rq + {0..7}
  const int K    = layer ? 512 : 384;
  const int KW   = K >> 2;           // per-wave K range
  const int k0w  = wv * KW;
  const int NSC  = KW >> 4;          // 16-k sub-chunks per wave: 8 / 6

  // ---- one-time W staging: [k][64col], col c -> global row (c&3)*256 + u0 + (c>>2) ----
  {
    const int c = tid & 63;
    const int kq4 = (tid >> 6) << 2;
    const int row = (c & 3)*256 + u0 + (c >> 2);
    for (int kb = 0; kb < K; kb += 16) {
      const int kg = kb + kq4;
      const float* wp; int wstr, woff;
      if (layer == 0) {
        if (kg < 128) { wp = Wih0; wstr = 128; woff = kg; }
        else          { wp = Whh0; wstr = 256; woff = kg - 128; }
      } else {
        if (kg < 256) { wp = Wih1; wstr = 256; woff = kg; }
        else          { wp = Whh1; wstr = 256; woff = kg - 256; }
      }
      float4 v = *reinterpret_cast<const float4*>(wp + row*wstr + woff);
      w_lds[(kg+0)*64 + c] = v.x;
      w_lds[(kg+1)*64 + c] = v.y;
      w_lds[(kg+2)*64 + c] = v.z;
      w_lds[(kg+3)*64 + c] = v.w;
    }
  }

  // biases + persistent cell state (meaningful only in finisher threads)
  const float* bi_p = layer ? bih1 : bih0;
  const float* bh_p = layer ? bhh1 : bhh0;
  float bsum[2][4];
#pragma unroll
  for (int uj = 0; uj < 2; ++uj) {
    const int uu = u0 + 2*rq + uj;
#pragma unroll
    for (int gt = 0; gt < 4; ++gt)
      bsum[uj][gt] = bi_p[gt*256 + uu] + bh_p[gt*256 + uu];
  }
  float c_reg[2][4] = {{0.f,0.f,0.f,0.f},{0.f,0.f,0.f,0.f}};

  float* aw = a_lds + (wv << 10);    // wave-private 1024-float region (2 halves)
  const int bl = lane & 31, jq = lane >> 5;
  unsigned* slot = bar + ((g*32 + role) << 4);
  unsigned* gbase = bar + ((g*32) << 4);

  // finisher role (static across steps): w0 keeps b0-15 (lanes<32), w1 keeps b16-31
  const bool is_finisher = (wv < 2) && ((wv == 0) ? (lane < 32) : (lane >= 32));
  const bool is_giver    = (wv < 2) && !((wv == 0) ? (lane < 32) : (lane >= 32));

  float4 av0, av1;
#define PF_A(kcg, ss) do {                                                        \
    const int kc_ = (kcg);                                                        \
    const float* ap; int astr, aoff; bool at_;                                    \
    if (layer == 0) {                                                             \
      if (kc_ < 128) { ap = X + (ss)*32768;         astr = 128; aoff = kc_;       at_ = false; } \
      else           { ap = h0buf + ((ss)&1)*65536; astr = 256; aoff = kc_ - 128; at_ = true; }  \
    } else {                                                                      \
      if (kc_ < 256) { ap = h0buf + ((ss)&1)*65536; astr = 256; aoff = kc_;       at_ = true; }  \
      else           { ap = h1buf + ((ss)&1)*65536; astr = 256; aoff = kc_ - 256; at_ = true; }  \
    }                                                                             \
    const float* base_ = ap + (b0 + bl)*astr + aoff + 4*jq;                       \
    if (at_) {                                                                    \
      float2 p0 = h_load2(base_),     p1 = h_load2(base_ + 2);                    \
      float2 p2 = h_load2(base_ + 8), p3 = h_load2(base_ + 10);                   \
      av0 = make_float4(p0.x, p0.y, p1.x, p1.y);                                  \
      av1 = make_float4(p2.x, p2.y, p3.x, p3.y);                                  \
    } else {                                                                      \
      av0 = *reinterpret_cast<const float4*>(base_);                              \
      av1 = *reinterpret_cast<const float4*>(base_ + 8);                          \
    }                                                                             \
  } while (0)

  // X-sourced chunk-0 waves may prefetch across the barrier (immutable data)
  const bool pf_early = (layer == 0) && (k0w + 16 <= 128);
  if (pf_early) { PF_A(k0w, 0); }

  __syncthreads();   // w_lds ready

#pragma unroll 1
  for (int s = 0; s <= 77; ++s) {
    const bool active = layer ? (s >= 1) : (s < 77);
    if (active) {
      if (!pf_early) { PF_A(k0w, s); }   // h-sourced: after barrier observation
      float acc[4][8];
#pragma unroll
      for (int i = 0; i < 4; ++i)
#pragma unroll
        for (int j = 0; j < 8; ++j) acc[i][j] = 0.f;

#pragma unroll 1
      for (int sc = 0; sc < NSC; ++sc) {
        float* awc = aw + ((sc & 1) << 9);   // double-buffer half
        awc[(4*jq+0)*32 + bl]  = av0.x;
        awc[(4*jq+1)*32 + bl]  = av0.y;
        awc[(4*jq+2)*32 + bl]  = av0.z;
        awc[(4*jq+3)*32 + bl]  = av0.w;
        awc[(4*jq+8)*32 + bl]  = av1.x;
        awc[(4*jq+9)*32 + bl]  = av1.y;
        awc[(4*jq+10)*32 + bl] = av1.z;
        awc[(4*jq+11)*32 + bl] = av1.w;
        if (sc + 1 < NSC) { PF_A(k0w + 16*(sc+1), s); }
        const float* wk = w_lds + ((k0w + (sc << 4)) << 6);
#pragma unroll
        for (int kl = 0; kl < 16; ++kl) {
          const float4 a4  = *reinterpret_cast<const float4*>(awc + kl*32 + 4*bq);
          const float4 wA  = *reinterpret_cast<const float4*>(wk + (kl<<6) + 8*rq);
          const float4 wB  = *reinterpret_cast<const float4*>(wk + (kl<<6) + 8*rq + 4);
          acc[0][0] += a4.x*wA.x; acc[0][1] += a4.x*wA.y; acc[0][2] += a4.x*wA.z; acc[0][3] += a4.x*wA.w;
          acc[0][4] += a4.x*wB.x; acc[0][5] += a4.x*wB.y; acc[0][6] += a4.x*wB.z; acc[0][7] += a4.x*wB.w;
          acc[1][0] += a4.y*wA.x; acc[1][1] += a4.y*wA.y; acc[1][2] += a4.y*wA.z; acc[1][3] += a4.y*wA.w;
          acc[1][4] += a4.y*wB.x; acc[1][5] += a4.y*wB.y; acc[1][6] += a4.y*wB.z; acc[1][7] += a4.y*wB.w;
          acc[2][0] += a4.z*wA.x; acc[2][1] += a4.z*wA.y; acc[2][2] += a4.z*wA.z; acc[2][3] += a4.z*wA.w;
          acc[2][4] += a4.z*wB.x; acc[2][5] += a4.z*wB.y; acc[2][6] += a4.z*wB.z; acc[2][7] += a4.z*wB.w;
          acc[3][0] += a4.w*wA.x; acc[3][1] += a4.w*wA.y; acc[3][2] += a4.w*wA.z; acc[3][3] += a4.w*wA.w;
          acc[3][4] += a4.w*wB.x; acc[3][5] += a4.w*wB.y; acc[3][6] += a4.w*wB.z; acc[3][7] += a4.w*wB.w;
        }
      }

      // ---- lane-major parallel reduction (3 syncs, zero-conflict addressing) ----
      __syncthreads();
      if (wv == 2) {
#pragma unroll
        for (int qi = 0; qi < 8; ++qi) {
          const int bi = qi >> 1, c0 = (qi & 1) << 2;
          *reinterpret_cast<float4*>(&red[((qi<<6) + lane) << 2]) =
            make_float4(acc[bi][c0], acc[bi][c0+1], acc[bi][c0+2], acc[bi][c0+3]);
        }
      } else if (wv == 3) {
#pragma unroll
        for (int qi = 0; qi < 8; ++qi) {
          const int bi = qi >> 1, c0 = (qi & 1) << 2;
          *reinterpret_cast<float4*>(&a_lds[((qi<<6) + lane) << 2]) =
            make_float4(acc[bi][c0], acc[bi][c0+1], acc[bi][c0+2], acc[bi][c0+3]);
        }
      }
      __syncthreads();
      if (wv < 2) {
        const float* src = (wv == 0) ? red : a_lds;   // w0 += w2-part, w1 += w3-part
#pragma unroll
        for (int qi = 0; qi < 8; ++qi) {
          const int bi = qi >> 1, c0 = (qi & 1) << 2;
          float4 v = *reinterpret_cast<const float4*>(&src[((qi<<6) + lane) << 2]);
          acc[bi][c0]   += v.x;
          acc[bi][c0+1] += v.y;
          acc[bi][c0+2] += v.z;
          acc[bi][c0+3] += v.w;
        }
        if (is_giver) {   // hand half-sums to the other finisher wave (disjoint lanes)
#pragma unroll
          for (int qi = 0; qi < 8; ++qi) {
            const int bi = qi >> 1, c0 = (qi & 1) << 2;
            *reinterpret_cast<float4*>(&a_lds[2048 + (((qi<<6) + lane) << 2)]) =
              make_float4(acc[bi][c0], acc[bi][c0+1], acc[bi][c0+2], acc[bi][c0+3]);
          }
        }
      }
      __syncthreads();
      if (is_finisher) {
        float* __restrict__ hw = (layer ? h1buf : h0buf) + ((s+1)&1)*65536;
#pragma unroll
        for (int bi = 0; bi < 4; ++bi) {
          float4 v0 = *reinterpret_cast<const float4*>(&a_lds[2048 + ((((2*bi)<<6)   + lane) << 2)]);
          float4 v1 = *reinterpret_cast<const float4*>(&a_lds[2048 + ((((2*bi+1)<<6) + lane) << 2)]);
          acc[bi][0]+=v0.x; acc[bi][1]+=v0.y; acc[bi][2]+=v0.z; acc[bi][3]+=v0.w;
          acc[bi][4]+=v1.x; acc[bi][5]+=v1.y; acc[bi][6]+=v1.z; acc[bi][7]+=v1.w;
          float hv[2];
#pragma unroll
          for (int uj = 0; uj < 2; ++uj) {
            float gi = acc[bi][4*uj+0] + bsum[uj][0];
            float gf = acc[bi][4*uj+1] + bsum[uj][1];
            float gg = acc[bi][4*uj+2] + bsum[uj][2];
            float go = acc[bi][4*uj+3] + bsum[uj][3];
            float si = 1.f/(1.f + expf(-gi));
            float sf = 1.f/(1.f + expf(-gf));
            float so = 1.f/(1.f + expf(-go));
            float tg = tanhf(gg);
            float cn = sf*c_reg[uj][bi] + si*tg;
            c_reg[uj][bi] = cn;
            hv[uj] = so*tanhf(cn);
          }
          h_store2(hw + (b0 + 4*bq + bi)*256 + u0 + 2*rq, hv[0], hv[1]);
        }
        // no fence: sc1 stores drained by the vmcnt(0) in the next __syncthreads,
        // before tid0's slot release (program order within wave 0).
      }
    }
    if (s == 77) break;
    __syncthreads();                // all waves done; drains finisher h-stores
    if (tid == 0)
      __hip_atomic_store(slot, (unsigned)(s+1), __ATOMIC_RELAXED, __HIP_MEMORY_SCOPE_AGENT);
    // pre-spin prefetch of next step's chunk-0 A for X-sourced waves (race-free)
    if (pf_early && (s + 1 < 77)) { PF_A(k0w, s + 1); }
    if (wv == 0) {
      const unsigned tgt = (unsigned)(s+1);
      for (;;) {
        unsigned v = tgt;
        if (lane < 32)
          v = __hip_atomic_load(gbase + (lane << 4), __ATOMIC_RELAXED, __HIP_MEMORY_SCOPE_AGENT);
        if (__all(v >= tgt)) break;
        __builtin_amdgcn_s_sleep(2);
      }
      asm volatile("" ::: "memory");   // no hoisting h-loads above the spin
    }
    __syncthreads();
    if (layer == 1) {
      const int ns = s + 1;
      if (ns >= 1 && ns <= 77) PF_A(0, ns);   // h0-sourced: after barrier observation
    }
  }
#undef PF_A
}

// ---------------- FC: C = act(A @ W^T + b), M=256 ----------------
__global__ __launch_bounds__(256) void k_fc(const float* __restrict__ A,
    const float* __restrict__ W, const float* __restrict__ bias,
    float* __restrict__ Cout, int N, int K, int kshift, int dorelu) {
  __shared__ __align__(16) float sa[16*516];
  int m0 = blockIdx.y * 16;
  int n = blockIdx.x * 16 + (threadIdx.x & 15);
  int m = threadIdx.x >> 4;
  int stride = K + 4;
  for (int i = threadIdx.x; i < 16*K; i += 256) {
    int mm = i >> kshift;
    int kk = i - (mm << kshift);
    sa[mm*stride + kk] = A[(m0+mm)*K + kk];
  }
  __syncthreads();
  const float4* wr = reinterpret_cast<const float4*>(W + n*K);
  const float4* ar = reinterpret_cast<const float4*>(sa + m*stride);
  float acc = 0.f;
  int kq4 = K >> 2;
  for (int kq = 0; kq < kq4; ++kq) {
    float4 wv = wr[kq], av = ar[kq];
    acc += av.x*wv.x + av.y*wv.y + av.z*wv.z + av.w*wv.w;
  }
  acc += bias[n];
  if (dorelu) acc = fmaxf(acc, 0.f);
  Cout[(m0+m)*N + n] = acc;
}

extern "C" void kernel_launch(void* const* d_in, const int* in_sizes, int n_in,
                              void* d_out, int out_size, void* d_ws, size_t ws_size,
                              hipStream_t stream) {
  const float* x       = (const float*)d_in[0];
  const float* conv_w0 = (const float*)d_in[1];
  const float* conv_b0 = (const float*)d_in[2];
  const float* bn_g0   = (const float*)d_in[3];
  const float* bn_b0   = (const float*)d_in[4];
  const float* bn_m0   = (const float*)d_in[5];
  const float* bn_v0   = (const float*)d_in[6];
  const float* conv_w1 = (const float*)d_in[7];
  const float* conv_b1 = (const float*)d_in[8];
  const float* bn_g1   = (const float*)d_in[9];
  const float* bn_b1   = (const float*)d_in[10];
  const float* bn_m1   = (const float*)d_in[11];
  const float* bn_v1   = (const float*)d_in[12];
  const float* Wih0    = (const float*)d_in[13];
  const float* Whh0    = (const float*)d_in[14];
  const float* bih0    = (const float*)d_in[15];
  const float* bhh0    = (const float*)d_in[16];
  const float* Wih1    = (const float*)d_in[17];
  const float* Whh1    = (const float*)d_in[18];
  const float* bih1    = (const float*)d_in[19];
  const float* bhh1    = (const float*)d_in[20];
  const float* fc0_w   = (const float*)d_in[21];
  const float* fc0_b   = (const float*)d_in[22];
  const float* fc1_w   = (const float*)d_in[23];
  const float* fc1_b   = (const float*)d_in[24];
  const float* out_w   = (const float*)d_in[25];
  const float* out_b   = (const float*)d_in[26];
  float* ws = (float*)d_ws;
  float* out = (float*)d_out;

  static float h_consts[160];
  compute_consts(h_consts);
  hipMemcpyAsync(ws + OFF_CONST, h_consts, 160*sizeof(float), hipMemcpyHostToDevice, stream);
  hipMemsetAsync(ws + OFF_H0, 0, 393216*sizeof(float), stream);
  hipMemsetAsync(ws + OFF_BAR, 0, 16384, stream);   // barrier slot lines -> 0

  k_sgconv0<<<dim3(3, BATCH), 256, 0, stream>>>(x, ws + OFF_CONST, conv_w0, conv_b0,
                                                bn_g0, bn_b0, bn_m0, bn_v0, ws + OFF_Y1);
  k_conv1_gemm<<<620, 256, 0, stream>>>(ws + OFF_Y1, conv_w1, conv_b1, ws + OFF_TMP);
  k_pool1<<<9856, 256, 0, stream>>>(ws + OFF_TMP, bn_g1, bn_b1, bn_m1, bn_v1, ws + OFF_X);
  k_lstm_persist<<<256, 256, 0, stream>>>(ws + OFF_X, Wih0, Whh0, bih0, bhh0,
                                          Wih1, Whh1, bih1, bhh1,
                                          ws + OFF_H0, ws + OFF_H1,
                                          (unsigned*)(ws + OFF_BAR));
  k_fc<<<dim3(32, 16), 256, 0, stream>>>(ws + OFF_H1, fc0_w, fc0_b, ws + OFF_Z0, 512, 256, 8, 1);
  k_fc<<<dim3(32, 16), 256, 0, stream>>>(ws + OFF_Z0, fc1_w, fc1_b, ws + OFF_Z1, 512, 512, 9, 1);
  k_fc<<<dim3(16, 16), 256, 0, stream>>>(ws + OFF_Z1, out_w, out_b, out, 256, 512, 9, 0);
}

// Round 14
// 1176.951 us; speedup vs baseline: 1.0212x; 1.0212x over previous
//
#include <hip/hip_runtime.h>
#include <math.h>

#define BATCH 256
#define LEN   10000
#define C0 64
#define P0 624
#define T1 155
#define P1 77

// ws offsets (in floats)
#define OFF_CONST 0
#define OFF_BAR   160        // barrier slot lines: 8 groups x 32 members x 64B = 16KB
#define OFF_Y1    2560160
#define OFF_X     12783776
#define OFF_H0    15306912
#define OFF_C0    15437984
#define OFF_H1    15503520
#define OFF_C1    15634592
#define OFF_Z0    15700128
#define OFF_Z1    15831200
#define OFF_TMP   15962272

// ---------------- host-side savgol constants ----------------
static void invert4(const double A[4][4], double inv[4][4]) {
  double M[4][8];
  for (int i = 0; i < 4; ++i)
    for (int j = 0; j < 4; ++j) { M[i][j] = A[i][j]; M[i][j+4] = (i==j) ? 1.0 : 0.0; }
  for (int col = 0; col < 4; ++col) {
    int p = col;
    for (int r = col+1; r < 4; ++r) if (fabs(M[r][col]) > fabs(M[p][col])) p = r;
    if (p != col) for (int j = 0; j < 8; ++j) { double t = M[col][j]; M[col][j] = M[p][j]; M[p][j] = t; }
    double d = M[col][col];
    for (int j = 0; j < 8; ++j) M[col][j] /= d;
    for (int r = 0; r < 4; ++r) if (r != col) {
      double f = M[r][col];
      for (int j = 0; j < 8; ++j) M[r][j] -= f * M[col][j];
    }
  }
  for (int i = 0; i < 4; ++i) for (int j = 0; j < 4; ++j) inv[i][j] = M[i][j+4];
}

static void compute_consts(float* out) {
  {
    double V[11][4], A[4][4], inv[4][4];
    for (int w = 0; w < 11; ++w) { double t = (double)(w-5), pw = 1.0; for (int m = 0; m < 4; ++m) { V[w][m] = pw; pw *= t; } }
    for (int m = 0; m < 4; ++m) for (int n = 0; n < 4; ++n) { double s = 0; for (int w = 0; w < 11; ++w) s += V[w][m]*V[w][n]; A[m][n] = s; }
    invert4(A, inv);
    for (int w = 0; w < 11; ++w) { double s = 0; for (int m = 0; m < 4; ++m) s += inv[0][m]*V[w][m]; out[w] = (float)s; }
  }
  {
    double V[11][4], A[4][4], inv[4][4], pe[4][11];
    for (int w = 0; w < 11; ++w) { double t = (double)w, pw = 1.0; for (int m = 0; m < 4; ++m) { V[w][m] = pw; pw *= t; } }
    for (int m = 0; m < 4; ++m) for (int n = 0; n < 4; ++n) { double s = 0; for (int w = 0; w < 11; ++w) s += V[w][m]*V[w][n]; A[m][n] = s; }
    invert4(A, inv);
    for (int m = 0; m < 4; ++m) for (int w = 0; w < 11; ++w) { double s = 0; for (int n = 0; n < 4; ++n) s += inv[m][n]*V[w][n]; pe[m][w] = s; }
    for (int w = 0; w < 11; ++w) for (int k = 0; k < 5; ++k) {
      double s = 0, pk = 1.0;
      for (int m = 0; m < 4; ++m) { s += pe[m][w]*pk; pk *= (double)k; }
      out[16 + w*5 + k] = (float)s;
    }
    for (int w = 0; w < 11; ++w) for (int k = 0; k < 5; ++k) {
      double tv = (double)(6+k), s = 0, pk = 1.0;
      for (int m = 0; m < 4; ++m) { s += pe[m][w]*pk; pk *= tv; }
      out[80 + w*5 + k] = (float)s;
    }
  }
}

// ---------------- fused savgol + conv0 + relu + pool2 + bn: x -> y1 (256,64,624) ----------------
__global__ __launch_bounds__(256) void k_sgconv0(const float* __restrict__ x,
    const float* __restrict__ Cc,
    const float* __restrict__ w0, const float* __restrict__ cb0,
    const float* __restrict__ bg0, const float* __restrict__ bb0,
    const float* __restrict__ bm0, const float* __restrict__ bv0,
    float* __restrict__ y1) {
  __shared__ float sw[1024];
  __shared__ float s_sc[64], s_off[64], s_cb[64];
  int tid = threadIdx.x;
  for (int i = tid; i < 1024; i += 256) sw[i] = w0[i];
  if (tid < 64) {
    float sc = bg0[tid] * rsqrtf(bv0[tid] + 1e-5f);
    s_sc[tid] = sc;
    s_off[tid] = bb0[tid] - bm0[tid]*sc;
    s_cb[tid] = cb0[tid];
  }
  __syncthreads();
  int b = blockIdx.y;
  int uu = blockIdx.x*256 + tid;
  if (uu >= P0) return;
  const float* xb = x + b*LEN;
  float hC[11];
#pragma unroll
  for (int w = 0; w < 11; ++w) hC[w] = Cc[w];
  float iv[24];
  if (uu == 0) {
    float xx[32];
    const float4* p = reinterpret_cast<const float4*>(xb);
#pragma unroll
    for (int j = 0; j < 8; ++j) { float4 v = p[j]; xx[4*j]=v.x; xx[4*j+1]=v.y; xx[4*j+2]=v.z; xx[4*j+3]=v.w; }
#pragma unroll
    for (int j = 0; j < 24; ++j) {
      float s = 0.f;
      if (j < 5) {
        for (int w = 0; w < 11; ++w) s += xx[w] * Cc[16 + w*5 + j];
      } else {
        for (int w = 0; w < 11; ++w) s += xx[j-5+w] * hC[w];
      }
      iv[j] = s;
    }
  } else {
    float xx[40];
    const float4* p = reinterpret_cast<const float4*>(xb + 16*uu - 8);
#pragma unroll
    for (int j = 0; j < 10; ++j) { float4 v = p[j]; xx[4*j]=v.x; xx[4*j+1]=v.y; xx[4*j+2]=v.z; xx[4*j+3]=v.w; }
#pragma unroll
    for (int j = 0; j < 24; ++j) {
      float s = 0.f;
#pragma unroll
      for (int w = 0; w < 11; ++w) s += xx[j+3+w] * hC[w];
      iv[j] = s;
    }
  }
  int obase = b*(C0*P0) + uu;
  for (int oc = 0; oc < 64; ++oc) {
    float bias = s_cb[oc];
    float s0 = bias, s1 = bias;
#pragma unroll
    for (int k = 0; k < 16; ++k) {
      float wk = sw[oc*16 + k];
      s0 += iv[k]   * wk;
      s1 += iv[k+8] * wk;
    }
    float pm = fmaxf(fmaxf(s0, 0.f), fmaxf(s1, 0.f));
    y1[obase + oc*P0] = pm*s_sc[oc] + s_off[oc];
  }
}

// ---------------- conv1 GEMM + FUSED relu/pool2/bn: y1 -> X (77,256,128) ----------------
// m' = b*156 + t padded index space (624 blocks x 64 m'). t=155 is a dummy row
// (addresses clamped, never stored). Thread-held register pairs acc[2i]/acc[2i+1]
// are exactly pool pairs (m' even-aligned; pairs never straddle block or batch),
// so relu+maxpool+bn happen in the epilogue and k_pool1 + the 30MB tmp round-trip
// are eliminated.
__global__ __launch_bounds__(256) void k_conv1_gemm(const float* __restrict__ y1,
    const float* __restrict__ w1, const float* __restrict__ cb1,
    const float* __restrict__ bg1, const float* __restrict__ bb1,
    const float* __restrict__ bm1, const float* __restrict__ bv1,
    float* __restrict__ X) {
  __shared__ __align__(16) float a_t[32*66];
  __shared__ __align__(16) float w_t[32*132];
  int m0 = blockIdx.x * 64;
  int tid = threadIdx.x;
  int sa_s = tid & 7, sa_r = tid >> 3;
  int un = tid & 31, mq = tid >> 5;
  int ybase[2];
#pragma unroll
  for (int i = 0; i < 2; ++i) {
    int m = m0 + sa_r + 32*i;
    int b = m / 156, t = m - b*156;
    if (t > 154) t = 154;              // dummy row: load valid data, never stored
    ybase[i] = b*(C0*P0) + 4*t;
  }
  int ci_off = sa_s >> 1, kkq = (sa_s & 1) * 4;
  float4 av[2], wv[4];
  float acc[8][4] = {{0.f}};
  int swzw = sa_s << 2;

#define CONV1_PREFETCH(cidx) do {                                                   \
    int kc = (cidx) * 32;                                                           \
    int ci0 = kc >> 3;                                                              \
    av[0] = *reinterpret_cast<const float4*>(y1 + ybase[0] + (ci0 + ci_off)*P0 + kkq); \
    av[1] = *reinterpret_cast<const float4*>(y1 + ybase[1] + (ci0 + ci_off)*P0 + kkq); \
    _Pragma("unroll")                                                               \
    for (int i = 0; i < 4; ++i)                                                     \
      wv[i] = *reinterpret_cast<const float4*>(w1 + (sa_r + 32*i)*512 + kc + 4*sa_s); \
  } while (0)

  CONV1_PREFETCH(0);
  for (int cidx = 0; cidx < 16; ++cidx) {
    if (cidx) __syncthreads();
#pragma unroll
    for (int i = 0; i < 2; ++i) {
      int col = sa_r + 32*i;
      a_t[(4*sa_s+0)*66 + col] = av[i].x;
      a_t[(4*sa_s+1)*66 + col] = av[i].y;
      a_t[(4*sa_s+2)*66 + col] = av[i].z;
      a_t[(4*sa_s+3)*66 + col] = av[i].w;
    }
#pragma unroll
    for (int i = 0; i < 4; ++i) {
      int colw = (sa_r + 32*i) ^ swzw;
      w_t[(4*sa_s+0)*132 + colw] = wv[i].x;
      w_t[(4*sa_s+1)*132 + colw] = wv[i].y;
      w_t[(4*sa_s+2)*132 + colw] = wv[i].z;
      w_t[(4*sa_s+3)*132 + colw] = wv[i].w;
    }
    __syncthreads();
    if (cidx + 1 < 16) { CONV1_PREFETCH(cidx + 1); }
#pragma unroll
    for (int k = 0; k < 32; ++k) {
      float4 w4 = *reinterpret_cast<const float4*>(&w_t[k*132 + ((4*un) ^ ((k>>2)<<2))]);
      float2 a2[4];
#pragma unroll
      for (int i = 0; i < 4; ++i)
        a2[i] = *reinterpret_cast<const float2*>(&a_t[k*66 + 2*mq + 16*i]);
#pragma unroll
      for (int i = 0; i < 4; ++i) {
        acc[2*i+0][0] += a2[i].x*w4.x; acc[2*i+0][1] += a2[i].x*w4.y;
        acc[2*i+0][2] += a2[i].x*w4.z; acc[2*i+0][3] += a2[i].x*w4.w;
        acc[2*i+1][0] += a2[i].y*w4.x; acc[2*i+1][1] += a2[i].y*w4.y;
        acc[2*i+1][2] += a2[i].y*w4.z; acc[2*i+1][3] += a2[i].y*w4.w;
      }
    }
  }
#undef CONV1_PREFETCH
  // fused epilogue: bias -> relu -> pool(pair) -> bn -> X[u][b][oc]
  float4 bias = *reinterpret_cast<const float4*>(cb1 + 4*un);
  float4 g4 = *reinterpret_cast<const float4*>(bg1 + 4*un);
  float4 v4 = *reinterpret_cast<const float4*>(bv1 + 4*un);
  float4 b4 = *reinterpret_cast<const float4*>(bb1 + 4*un);
  float4 m4 = *reinterpret_cast<const float4*>(bm1 + 4*un);
  float4 sc, off;
  sc.x = g4.x * rsqrtf(v4.x + 1e-5f);  off.x = b4.x - m4.x*sc.x;
  sc.y = g4.y * rsqrtf(v4.y + 1e-5f);  off.y = b4.y - m4.y*sc.y;
  sc.z = g4.z * rsqrtf(v4.z + 1e-5f);  off.z = b4.z - m4.z*sc.z;
  sc.w = g4.w * rsqrtf(v4.w + 1e-5f);  off.w = b4.w - m4.w*sc.w;
#pragma unroll
  for (int i = 0; i < 4; ++i) {
    int m = m0 + 2*mq + 16*i;          // even; pair (m, m+1)
    int b = m / 156, t = m - b*156;    // t even; pair (t, t+1), same b
    if (t <= 152) {                    // u = t/2 in [0,76]
      int u = t >> 1;
      float4 o;
      o.x = fmaxf(0.f, fmaxf(acc[2*i][0], acc[2*i+1][0]) + bias.x) * sc.x + off.x;
      o.y = fmaxf(0.f, fmaxf(acc[2*i][1], acc[2*i+1][1]) + bias.y) * sc.y + off.y;
      o.z = fmaxf(0.f, fmaxf(acc[2*i][2], acc[2*i+1][2]) + bias.z) * sc.z + off.z;
      o.w = fmaxf(0.f, fmaxf(acc[2*i][3], acc[2*i+1][3]) + bias.w) * sc.w + off.w;
      *reinterpret_cast<float4*>(X + u*32768 + b*128 + 4*un) = o;
    }
  }
}

// ---- fence-free h exchange: relaxed AGENT-scope 8B atomics (sc1, bypass per-XCD L2,
// coherent at L3). Proven r11: removing the per-step fences cut persist 1628->984us. ----
__device__ __forceinline__ float2 h_load2(const float* p) {
  unsigned long long v = __hip_atomic_load((const unsigned long long*)p,
                                           __ATOMIC_RELAXED, __HIP_MEMORY_SCOPE_AGENT);
  float2 r;
  r.x = __uint_as_float((unsigned)v);
  r.y = __uint_as_float((unsigned)(v >> 32));
  return r;
}
__device__ __forceinline__ void h_store2(float* p, float a, float b) {
  unsigned long long v = (unsigned long long)__float_as_uint(a)
                       | ((unsigned long long)__float_as_uint(b) << 32);
  __hip_atomic_store((unsigned long long*)p, v,
                     __ATOMIC_RELAXED, __HIP_MEMORY_SCOPE_AGENT);
}

// ---------------- persistent LSTM v6 (VERBATIM r11 best: 984us): fence-free h-exchange ----------------
// r12 (V7 parallel reduction): 1020us + 5.68M conflicts. r13 (V7b lane-major parallel
// reduction): 1018us, conflicts 0 but still worse than V6. Conclusion: the reduction
// tail is hidden; restructures cost what they save. This is the measured-best V6.
__global__ __launch_bounds__(256) void k_lstm_persist(
    const float* __restrict__ X,
    const float* __restrict__ Wih0, const float* __restrict__ Whh0,
    const float* __restrict__ bih0, const float* __restrict__ bhh0,
    const float* __restrict__ Wih1, const float* __restrict__ Whh1,
    const float* __restrict__ bih1, const float* __restrict__ bhh1,
    float* __restrict__ h0buf, float* __restrict__ h1buf,
    unsigned* bar) {
  __shared__ __align__(16) float w_lds[512*64];   // [k][col], col = 4*ulocal + gate
  __shared__ __align__(16) float a_lds[4*2*16*32];// per-wave 2x [16k][32b] (dbuf)
  __shared__ __align__(16) float red[2048];       // reduction buffer (one wave's acc)

  const int blk  = blockIdx.x;
  const int g    = blk & 7;          // b-tile / barrier group
  const int role = blk >> 3;         // 0..31
  const int layer = role >> 4;
  const int u0   = (role & 15) * 16;
  const int b0   = g * 32;
  const int tid  = threadIdx.x;
  const int wv   = tid >> 6;
  const int lane = tid & 63;
  const int bq   = lane >> 3;        // batches b0 + 4*bq + {0..3}
  const int rq   = lane & 7;         // cols 8*rq + {0..7}
  const int K    = layer ? 512 : 384;
  const int KW   = K >> 2;           // per-wave K range
  const int k0w  = wv * KW;
  const int NSC  = KW >> 4;          // 16-k sub-chunks per wave: 8 / 6

  // ---- one-time W staging: [k][64col], col c -> global row (c&3)*256 + u0 + (c>>2) ----
  {
    const int c = tid & 63;
    const int kq4 = (tid >> 6) << 2;
    const int row = (c & 3)*256 + u0 + (c >> 2);
    for (int kb = 0; kb < K; kb += 16) {
      const int kg = kb + kq4;
      const float* wp; int wstr, woff;
      if (layer == 0) {
        if (kg < 128) { wp = Wih0; wstr = 128; woff = kg; }
        else          { wp = Whh0; wstr = 256; woff = kg - 128; }
      } else {
        if (kg < 256) { wp = Wih1; wstr = 256; woff = kg; }
        else          { wp = Whh1; wstr = 256; woff = kg - 256; }
      }
      float4 v = *reinterpret_cast<const float4*>(wp + row*wstr + woff);
      w_lds[(kg+0)*64 + c] = v.x;
      w_lds[(kg+1)*64 + c] = v.y;
      w_lds[(kg+2)*64 + c] = v.z;
      w_lds[(kg+3)*64 + c] = v.w;
    }
  }

  // biases + persistent cell state (used by wave 0 only)
  const float* bi_p = layer ? bih1 : bih0;
  const float* bh_p = layer ? bhh1 : bhh0;
  float bsum[2][4];
#pragma unroll
  for (int uj = 0; uj < 2; ++uj) {
    const int uu = u0 + 2*rq + uj;
#pragma unroll
    for (int gt = 0; gt < 4; ++gt)
      bsum[uj][gt] = bi_p[gt*256 + uu] + bh_p[gt*256 + uu];
  }
  float c_reg[2][4] = {{0.f,0.f,0.f,0.f},{0.f,0.f,0.f,0.f}};

  float* aw = a_lds + (wv << 10);    // wave-private 1024-float region (2 halves)
  const int bl = lane & 31, jq = lane >> 5;
  unsigned* slot = bar + ((g*32 + role) << 4);
  unsigned* gbase = bar + ((g*32) << 4);

  float4 av0, av1;
#define PF_A(kcg, ss) do {                                                        \
    const int kc_ = (kcg);                                                        \
    const float* ap; int astr, aoff; bool at_;                                    \
    if (layer == 0) {                                                             \
      if (kc_ < 128) { ap = X + (ss)*32768;         astr = 128; aoff = kc_;       at_ = false; } \
      else           { ap = h0buf + ((ss)&1)*65536; astr = 256; aoff = kc_ - 128; at_ = true; }  \
    } else {                                                                      \
      if (kc_ < 256) { ap = h0buf + ((ss)&1)*65536; astr = 256; aoff = kc_;       at_ = true; }  \
      else           { ap = h1buf + ((ss)&1)*65536; astr = 256; aoff = kc_ - 256; at_ = true; }  \
    }                                                                             \
    const float* base_ = ap + (b0 + bl)*astr + aoff + 4*jq;                       \
    if (at_) {                                                                    \
      float2 p0 = h_load2(base_),     p1 = h_load2(base_ + 2);                    \
      float2 p2 = h_load2(base_ + 8), p3 = h_load2(base_ + 10);                   \
      av0 = make_float4(p0.x, p0.y, p1.x, p1.y);                                  \
      av1 = make_float4(p2.x, p2.y, p3.x, p3.y);                                  \
    } else {                                                                      \
      av0 = *reinterpret_cast<const float4*>(base_);                              \
      av1 = *reinterpret_cast<const float4*>(base_ + 8);                          \
    }                                                                             \
  } while (0)

  // X-sourced chunk-0 waves may prefetch across the barrier (immutable data)
  const bool pf_early = (layer == 0) && (k0w + 16 <= 128);
  if (pf_early) { PF_A(k0w, 0); }

  __syncthreads();   // w_lds ready

#pragma unroll 1
  for (int s = 0; s <= 77; ++s) {
    const bool active = layer ? (s >= 1) : (s < 77);
    if (active) {
      if (!pf_early) { PF_A(k0w, s); }   // h-sourced: after barrier observation
      float acc[4][8];
#pragma unroll
      for (int i = 0; i < 4; ++i)
#pragma unroll
        for (int j = 0; j < 8; ++j) acc[i][j] = 0.f;

#pragma unroll 1
      for (int sc = 0; sc < NSC; ++sc) {
        float* awc = aw + ((sc & 1) << 9);   // double-buffer half
        awc[(4*jq+0)*32 + bl]  = av0.x;
        awc[(4*jq+1)*32 + bl]  = av0.y;
        awc[(4*jq+2)*32 + bl]  = av0.z;
        awc[(4*jq+3)*32 + bl]  = av0.w;
        awc[(4*jq+8)*32 + bl]  = av1.x;
        awc[(4*jq+9)*32 + bl]  = av1.y;
        awc[(4*jq+10)*32 + bl] = av1.z;
        awc[(4*jq+11)*32 + bl] = av1.w;
        if (sc + 1 < NSC) { PF_A(k0w + 16*(sc+1), s); }
        const float* wk = w_lds + ((k0w + (sc << 4)) << 6);
#pragma unroll
        for (int kl = 0; kl < 16; ++kl) {
          const float4 a4  = *reinterpret_cast<const float4*>(awc + kl*32 + 4*bq);
          const float4 wA  = *reinterpret_cast<const float4*>(wk + (kl<<6) + 8*rq);
          const float4 wB  = *reinterpret_cast<const float4*>(wk + (kl<<6) + 8*rq + 4);
          acc[0][0] += a4.x*wA.x; acc[0][1] += a4.x*wA.y; acc[0][2] += a4.x*wA.z; acc[0][3] += a4.x*wA.w;
          acc[0][4] += a4.x*wB.x; acc[0][5] += a4.x*wB.y; acc[0][6] += a4.x*wB.z; acc[0][7] += a4.x*wB.w;
          acc[1][0] += a4.y*wA.x; acc[1][1] += a4.y*wA.y; acc[1][2] += a4.y*wA.z; acc[1][3] += a4.y*wA.w;
          acc[1][4] += a4.y*wB.x; acc[1][5] += a4.y*wB.y; acc[1][6] += a4.y*wB.z; acc[1][7] += a4.y*wB.w;
          acc[2][0] += a4.z*wA.x; acc[2][1] += a4.z*wA.y; acc[2][2] += a4.z*wA.z; acc[2][3] += a4.z*wA.w;
          acc[2][4] += a4.z*wB.x; acc[2][5] += a4.z*wB.y; acc[2][6] += a4.z*wB.z; acc[2][7] += a4.z*wB.w;
          acc[3][0] += a4.w*wA.x; acc[3][1] += a4.w*wA.y; acc[3][2] += a4.w*wA.z; acc[3][3] += a4.w*wA.w;
          acc[3][4] += a4.w*wB.x; acc[3][5] += a4.w*wB.y; acc[3][6] += a4.w*wB.z; acc[3][7] += a4.w*wB.w;
        }
      }

      // ---- cross-wave K reduction: w3 -> w2 -> w1 -> w0 (8KB in-place) ----
      __syncthreads();
      if (wv == 3) {
#pragma unroll
        for (int qi = 0; qi < 8; ++qi) {
          const int bi = qi >> 1, c0 = (qi & 1) << 2;
          *reinterpret_cast<float4*>(&red[((qi<<6) + lane) << 2]) =
            make_float4(acc[bi][c0], acc[bi][c0+1], acc[bi][c0+2], acc[bi][c0+3]);
        }
      }
      __syncthreads();
      if (wv == 2) {
#pragma unroll
        for (int qi = 0; qi < 8; ++qi) {
          const int bi = qi >> 1, c0 = (qi & 1) << 2;
          float4 v = *reinterpret_cast<const float4*>(&red[((qi<<6) + lane) << 2]);
          *reinterpret_cast<float4*>(&red[((qi<<6) + lane) << 2]) =
            make_float4(acc[bi][c0]+v.x, acc[bi][c0+1]+v.y, acc[bi][c0+2]+v.z, acc[bi][c0+3]+v.w);
        }
      }
      __syncthreads();
      if (wv == 1) {
#pragma unroll
        for (int qi = 0; qi < 8; ++qi) {
          const int bi = qi >> 1, c0 = (qi & 1) << 2;
          float4 v = *reinterpret_cast<const float4*>(&red[((qi<<6) + lane) << 2]);
          *reinterpret_cast<float4*>(&red[((qi<<6) + lane) << 2]) =
            make_float4(acc[bi][c0]+v.x, acc[bi][c0+1]+v.y, acc[bi][c0+2]+v.z, acc[bi][c0+3]+v.w);
        }
      }
      __syncthreads();
      if (wv == 0) {
#pragma unroll
        for (int qi = 0; qi < 8; ++qi) {
          const int bi = qi >> 1, c0 = (qi & 1) << 2;
          float4 v = *reinterpret_cast<const float4*>(&red[((qi<<6) + lane) << 2]);
          acc[bi][c0]   += v.x;
          acc[bi][c0+1] += v.y;
          acc[bi][c0+2] += v.z;
          acc[bi][c0+3] += v.w;
        }
        float* __restrict__ hw = (layer ? h1buf : h0buf) + ((s+1)&1)*65536;
#pragma unroll
        for (int bi = 0; bi < 4; ++bi) {
          float hv[2];
#pragma unroll
          for (int uj = 0; uj < 2; ++uj) {
            float gi = acc[bi][4*uj+0] + bsum[uj][0];
            float gf = acc[bi][4*uj+1] + bsum[uj][1];
            float gg = acc[bi][4*uj+2] + bsum[uj][2];
            float go = acc[bi][4*uj+3] + bsum[uj][3];
            float si = 1.f/(1.f + expf(-gi));
            float sf = 1.f/(1.f + expf(-gf));
            float so = 1.f/(1.f + expf(-go));
            float tg = tanhf(gg);
            float cn = sf*c_reg[uj][bi] + si*tg;
            c_reg[uj][bi] = cn;
            hv[uj] = so*tanhf(cn);
          }
          h_store2(hw + (b0 + 4*bq + bi)*256 + u0 + 2*rq, hv[0], hv[1]);
        }
        // no fence: stores are agent-scope sc1 atomics (coherent at L3); the
        // vmcnt(0) drain inside the next __syncthreads orders them before the
        // slot release below (wave0 program order).
      }
    }
    if (s == 77) break;
    __syncthreads();                // all waves done; drains wave0's h-stores
    if (tid == 0)
      __hip_atomic_store(slot, (unsigned)(s+1), __ATOMIC_RELAXED, __HIP_MEMORY_SCOPE_AGENT);
    // pre-spin prefetch of next step's chunk-0 A for X-sourced waves (race-free)
    if (pf_early && (s + 1 < 77)) { PF_A(k0w, s + 1); }
    if (wv == 0) {
      const unsigned tgt = (unsigned)(s+1);
      for (;;) {
        unsigned v = tgt;
        if (lane < 32)
          v = __hip_atomic_load(gbase + (lane << 4), __ATOMIC_RELAXED, __HIP_MEMORY_SCOPE_AGENT);
        if (__all(v >= tgt)) break;
        __builtin_amdgcn_s_sleep(2);
      }
      asm volatile("" ::: "memory");   // compiler barrier: no hoisting h-loads above spin
    }
    __syncthreads();
    if (layer == 1) {
      const int ns = s + 1;
      if (ns >= 1 && ns <= 77) PF_A(0, ns);   // h0-sourced: after barrier observation
    }
  }
#undef PF_A
}

// ---------------- FC: C = act(A @ W^T + b), M=256 ----------------
__global__ __launch_bounds__(256) void k_fc(const float* __restrict__ A,
    const float* __restrict__ W, const float* __restrict__ bias,
    float* __restrict__ Cout, int N, int K, int kshift, int dorelu) {
  __shared__ __align__(16) float sa[16*516];
  int m0 = blockIdx.y * 16;
  int n = blockIdx.x * 16 + (threadIdx.x & 15);
  int m = threadIdx.x >> 4;
  int stride = K + 4;
  for (int i = threadIdx.x; i < 16*K; i += 256) {
    int mm = i >> kshift;
    int kk = i - (mm << kshift);
    sa[mm*stride + kk] = A[(m0+mm)*K + kk];
  }
  __syncthreads();
  const float4* wr = reinterpret_cast<const float4*>(W + n*K);
  const float4* ar = reinterpret_cast<const float4*>(sa + m*stride);
  float acc = 0.f;
  int kq4 = K >> 2;
  for (int kq = 0; kq < kq4; ++kq) {
    float4 wv = wr[kq], av = ar[kq];
    acc += av.x*wv.x + av.y*wv.y + av.z*wv.z + av.w*wv.w;
  }
  acc += bias[n];
  if (dorelu) acc = fmaxf(acc, 0.f);
  Cout[(m0+m)*N + n] = acc;
}

extern "C" void kernel_launch(void* const* d_in, const int* in_sizes, int n_in,
                              void* d_out, int out_size, void* d_ws, size_t ws_size,
                              hipStream_t stream) {
  const float* x       = (const float*)d_in[0];
  const float* conv_w0 = (const float*)d_in[1];
  const float* conv_b0 = (const float*)d_in[2];
  const float* bn_g0   = (const float*)d_in[3];
  const float* bn_b0   = (const float*)d_in[4];
  const float* bn_m0   = (const float*)d_in[5];
  const float* bn_v0   = (const float*)d_in[6];
  const float* conv_w1 = (const float*)d_in[7];
  const float* conv_b1 = (const float*)d_in[8];
  const float* bn_g1   = (const float*)d_in[9];
  const float* bn_b1   = (const float*)d_in[10];
  const float* bn_m1   = (const float*)d_in[11];
  const float* bn_v1   = (const float*)d_in[12];
  const float* Wih0    = (const float*)d_in[13];
  const float* Whh0    = (const float*)d_in[14];
  const float* bih0    = (const float*)d_in[15];
  const float* bhh0    = (const float*)d_in[16];
  const float* Wih1    = (const float*)d_in[17];
  const float* Whh1    = (const float*)d_in[18];
  const float* bih1    = (const float*)d_in[19];
  const float* bhh1    = (const float*)d_in[20];
  const float* fc0_w   = (const float*)d_in[21];
  const float* fc0_b   = (const float*)d_in[22];
  const float* fc1_w   = (const float*)d_in[23];
  const float* fc1_b   = (const float*)d_in[24];
  const float* out_w   = (const float*)d_in[25];
  const float* out_b   = (const float*)d_in[26];
  float* ws = (float*)d_ws;
  float* out = (float*)d_out;

  static float h_consts[160];
  compute_consts(h_consts);
  hipMemcpyAsync(ws + OFF_CONST, h_consts, 160*sizeof(float), hipMemcpyHostToDevice, stream);
  hipMemsetAsync(ws + OFF_H0, 0, 393216*sizeof(float), stream);
  hipMemsetAsync(ws + OFF_BAR, 0, 16384, stream);   // barrier slot lines -> 0

  k_sgconv0<<<dim3(3, BATCH), 256, 0, stream>>>(x, ws + OFF_CONST, conv_w0, conv_b0,
                                                bn_g0, bn_b0, bn_m0, bn_v0, ws + OFF_Y1);
  k_conv1_gemm<<<624, 256, 0, stream>>>(ws + OFF_Y1, conv_w1, conv_b1,
                                        bn_g1, bn_b1, bn_m1, bn_v1, ws + OFF_X);
  k_lstm_persist<<<256, 256, 0, stream>>>(ws + OFF_X, Wih0, Whh0, bih0, bhh0,
                                          Wih1, Whh1, bih1, bhh1,
                                          ws + OFF_H0, ws + OFF_H1,
                                          (unsigned*)(ws + OFF_BAR));
  k_fc<<<dim3(32, 16), 256, 0, stream>>>(ws + OFF_H1, fc0_w, fc0_b, ws + OFF_Z0, 512, 256, 8, 1);
  k_fc<<<dim3(32, 16), 256, 0, stream>>>(ws + OFF_Z0, fc1_w, fc1_b, ws + OFF_Z1, 512, 512, 9, 1);
  k_fc<<<dim3(16, 16), 256, 0, stream>>>(ws + OFF_Z1, out_w, out_b, out, 256, 512, 9, 0);
}

// Round 16
// 1168.525 us; speedup vs baseline: 1.0286x; 1.0072x over previous
//
#include <hip/hip_runtime.h>
#include <math.h>

#define BATCH 256
#define LEN   10000
#define C0 64
#define P0 624
#define T1 155
#define P1 77

// ws offsets (in floats)
#define OFF_CONST 0
#define OFF_BAR   160        // barrier slot lines: 8 groups x 32 members x 64B = 16KB
#define OFF_Y1    2560160
#define OFF_X     12783776
#define OFF_H0    15306912   // h0: THREE parities (3x65536) -> ends exactly at OFF_H1
#define OFF_H1    15503520   // h1: two parities
#define OFF_Z0    15700128
#define OFF_Z1    15831200
#define OFF_TMP   15962272

// ---------------- host-side savgol constants ----------------
static void invert4(const double A[4][4], double inv[4][4]) {
  double M[4][8];
  for (int i = 0; i < 4; ++i)
    for (int j = 0; j < 4; ++j) { M[i][j] = A[i][j]; M[i][j+4] = (i==j) ? 1.0 : 0.0; }
  for (int col = 0; col < 4; ++col) {
    int p = col;
    for (int r = col+1; r < 4; ++r) if (fabs(M[r][col]) > fabs(M[p][col])) p = r;
    if (p != col) for (int j = 0; j < 8; ++j) { double t = M[col][j]; M[col][j] = M[p][j]; M[p][j] = t; }
    double d = M[col][col];
    for (int j = 0; j < 8; ++j) M[col][j] /= d;
    for (int r = 0; r < 4; ++r) if (r != col) {
      double f = M[r][col];
      for (int j = 0; j < 8; ++j) M[r][j] -= f * M[col][j];
    }
  }
  for (int i = 0; i < 4; ++i) for (int j = 0; j < 4; ++j) inv[i][j] = M[i][j+4];
}

static void compute_consts(float* out) {
  {
    double V[11][4], A[4][4], inv[4][4];
    for (int w = 0; w < 11; ++w) { double t = (double)(w-5), pw = 1.0; for (int m = 0; m < 4; ++m) { V[w][m] = pw; pw *= t; } }
    for (int m = 0; m < 4; ++m) for (int n = 0; n < 4; ++n) { double s = 0; for (int w = 0; w < 11; ++w) s += V[w][m]*V[w][n]; A[m][n] = s; }
    invert4(A, inv);
    for (int w = 0; w < 11; ++w) { double s = 0; for (int m = 0; m < 4; ++m) s += inv[0][m]*V[w][m]; out[w] = (float)s; }
  }
  {
    double V[11][4], A[4][4], inv[4][4], pe[4][11];
    for (int w = 0; w < 11; ++w) { double t = (double)w, pw = 1.0; for (int m = 0; m < 4; ++m) { V[w][m] = pw; pw *= t; } }
    for (int m = 0; m < 4; ++m) for (int n = 0; n < 4; ++n) { double s = 0; for (int w = 0; w < 11; ++w) s += V[w][m]*V[w][n]; A[m][n] = s; }
    invert4(A, inv);
    for (int m = 0; m < 4; ++m) for (int w = 0; w < 11; ++w) { double s = 0; for (int n = 0; n < 4; ++n) s += inv[m][n]*V[w][n]; pe[m][w] = s; }
    for (int w = 0; w < 11; ++w) for (int k = 0; k < 5; ++k) {
      double s = 0, pk = 1.0;
      for (int m = 0; m < 4; ++m) { s += pe[m][w]*pk; pk *= (double)k; }
      out[16 + w*5 + k] = (float)s;
    }
    for (int w = 0; w < 11; ++w) for (int k = 0; k < 5; ++k) {
      double tv = (double)(6+k), s = 0, pk = 1.0;
      for (int m = 0; m < 4; ++m) { s += pe[m][w]*pk; pk *= tv; }
      out[80 + w*5 + k] = (float)s;
    }
  }
}

// ---------------- fused savgol + conv0 + relu + pool2 + bn: x -> y1 (256,64,624) ----------------
__global__ __launch_bounds__(256) void k_sgconv0(const float* __restrict__ x,
    const float* __restrict__ Cc,
    const float* __restrict__ w0, const float* __restrict__ cb0,
    const float* __restrict__ bg0, const float* __restrict__ bb0,
    const float* __restrict__ bm0, const float* __restrict__ bv0,
    float* __restrict__ y1) {
  __shared__ float sw[1024];
  __shared__ float s_sc[64], s_off[64], s_cb[64];
  int tid = threadIdx.x;
  for (int i = tid; i < 1024; i += 256) sw[i] = w0[i];
  if (tid < 64) {
    float sc = bg0[tid] * rsqrtf(bv0[tid] + 1e-5f);
    s_sc[tid] = sc;
    s_off[tid] = bb0[tid] - bm0[tid]*sc;
    s_cb[tid] = cb0[tid];
  }
  __syncthreads();
  int b = blockIdx.y;
  int uu = blockIdx.x*256 + tid;
  if (uu >= P0) return;
  const float* xb = x + b*LEN;
  float hC[11];
#pragma unroll
  for (int w = 0; w < 11; ++w) hC[w] = Cc[w];
  float iv[24];
  if (uu == 0) {
    float xx[32];
    const float4* p = reinterpret_cast<const float4*>(xb);
#pragma unroll
    for (int j = 0; j < 8; ++j) { float4 v = p[j]; xx[4*j]=v.x; xx[4*j+1]=v.y; xx[4*j+2]=v.z; xx[4*j+3]=v.w; }
#pragma unroll
    for (int j = 0; j < 24; ++j) {
      float s = 0.f;
      if (j < 5) {
        for (int w = 0; w < 11; ++w) s += xx[w] * Cc[16 + w*5 + j];
      } else {
        for (int w = 0; w < 11; ++w) s += xx[j-5+w] * hC[w];
      }
      iv[j] = s;
    }
  } else {
    float xx[40];
    const float4* p = reinterpret_cast<const float4*>(xb + 16*uu - 8);
#pragma unroll
    for (int j = 0; j < 10; ++j) { float4 v = p[j]; xx[4*j]=v.x; xx[4*j+1]=v.y; xx[4*j+2]=v.z; xx[4*j+3]=v.w; }
#pragma unroll
    for (int j = 0; j < 24; ++j) {
      float s = 0.f;
#pragma unroll
      for (int w = 0; w < 11; ++w) s += xx[j+3+w] * hC[w];
      iv[j] = s;
    }
  }
  int obase = b*(C0*P0) + uu;
  for (int oc = 0; oc < 64; ++oc) {
    float bias = s_cb[oc];
    float s0 = bias, s1 = bias;
#pragma unroll
    for (int k = 0; k < 16; ++k) {
      float wk = sw[oc*16 + k];
      s0 += iv[k]   * wk;
      s1 += iv[k+8] * wk;
    }
    float pm = fmaxf(fmaxf(s0, 0.f), fmaxf(s1, 0.f));
    y1[obase + oc*P0] = pm*s_sc[oc] + s_off[oc];
  }
}

// ---------------- conv1 GEMM + FUSED relu/pool2/bn: y1 -> X (77,256,128) ----------------
// m' = b*156 + t padded index space (624 blocks x 64 m'). t=155 is a dummy row
// (addresses clamped, never stored). Register pairs acc[2i]/acc[2i+1] are exactly
// pool pairs, so relu+maxpool+bn fuse into the epilogue (k_pool1 eliminated, r14).
__global__ __launch_bounds__(256) void k_conv1_gemm(const float* __restrict__ y1,
    const float* __restrict__ w1, const float* __restrict__ cb1,
    const float* __restrict__ bg1, const float* __restrict__ bb1,
    const float* __restrict__ bm1, const float* __restrict__ bv1,
    float* __restrict__ X) {
  __shared__ __align__(16) float a_t[32*66];
  __shared__ __align__(16) float w_t[32*132];
  int m0 = blockIdx.x * 64;
  int tid = threadIdx.x;
  int sa_s = tid & 7, sa_r = tid >> 3;
  int un = tid & 31, mq = tid >> 5;
  int ybase[2];
#pragma unroll
  for (int i = 0; i < 2; ++i) {
    int m = m0 + sa_r + 32*i;
    int b = m / 156, t = m - b*156;
    if (t > 154) t = 154;              // dummy row: load valid data, never stored
    ybase[i] = b*(C0*P0) + 4*t;
  }
  int ci_off = sa_s >> 1, kkq = (sa_s & 1) * 4;
  float4 av[2], wv[4];
  float acc[8][4] = {{0.f}};
  int swzw = sa_s << 2;

#define CONV1_PREFETCH(cidx) do {                                                   \
    int kc = (cidx) * 32;                                                           \
    int ci0 = kc >> 3;                                                              \
    av[0] = *reinterpret_cast<const float4*>(y1 + ybase[0] + (ci0 + ci_off)*P0 + kkq); \
    av[1] = *reinterpret_cast<const float4*>(y1 + ybase[1] + (ci0 + ci_off)*P0 + kkq); \
    _Pragma("unroll")                                                               \
    for (int i = 0; i < 4; ++i)                                                     \
      wv[i] = *reinterpret_cast<const float4*>(w1 + (sa_r + 32*i)*512 + kc + 4*sa_s); \
  } while (0)

  CONV1_PREFETCH(0);
  for (int cidx = 0; cidx < 16; ++cidx) {
    if (cidx) __syncthreads();
#pragma unroll
    for (int i = 0; i < 2; ++i) {
      int col = sa_r + 32*i;
      a_t[(4*sa_s+0)*66 + col] = av[i].x;
      a_t[(4*sa_s+1)*66 + col] = av[i].y;
      a_t[(4*sa_s+2)*66 + col] = av[i].z;
      a_t[(4*sa_s+3)*66 + col] = av[i].w;
    }
#pragma unroll
    for (int i = 0; i < 4; ++i) {
      int colw = (sa_r + 32*i) ^ swzw;
      w_t[(4*sa_s+0)*132 + colw] = wv[i].x;
      w_t[(4*sa_s+1)*132 + colw] = wv[i].y;
      w_t[(4*sa_s+2)*132 + colw] = wv[i].z;
      w_t[(4*sa_s+3)*132 + colw] = wv[i].w;
    }
    __syncthreads();
    if (cidx + 1 < 16) { CONV1_PREFETCH(cidx + 1); }
#pragma unroll
    for (int k = 0; k < 32; ++k) {
      float4 w4 = *reinterpret_cast<const float4*>(&w_t[k*132 + ((4*un) ^ ((k>>2)<<2))]);
      float2 a2[4];
#pragma unroll
      for (int i = 0; i < 4; ++i)
        a2[i] = *reinterpret_cast<const float2*>(&a_t[k*66 + 2*mq + 16*i]);
#pragma unroll
      for (int i = 0; i < 4; ++i) {
        acc[2*i+0][0] += a2[i].x*w4.x; acc[2*i+0][1] += a2[i].x*w4.y;
        acc[2*i+0][2] += a2[i].x*w4.z; acc[2*i+0][3] += a2[i].x*w4.w;
        acc[2*i+1][0] += a2[i].y*w4.x; acc[2*i+1][1] += a2[i].y*w4.y;
        acc[2*i+1][2] += a2[i].y*w4.z; acc[2*i+1][3] += a2[i].y*w4.w;
      }
    }
  }
#undef CONV1_PREFETCH
  // fused epilogue: bias -> relu -> pool(pair) -> bn -> X[u][b][oc]
  float4 bias = *reinterpret_cast<const float4*>(cb1 + 4*un);
  float4 g4 = *reinterpret_cast<const float4*>(bg1 + 4*un);
  float4 v4 = *reinterpret_cast<const float4*>(bv1 + 4*un);
  float4 b4 = *reinterpret_cast<const float4*>(bb1 + 4*un);
  float4 m4 = *reinterpret_cast<const float4*>(bm1 + 4*un);
  float4 sc, off;
  sc.x = g4.x * rsqrtf(v4.x + 1e-5f);  off.x = b4.x - m4.x*sc.x;
  sc.y = g4.y * rsqrtf(v4.y + 1e-5f);  off.y = b4.y - m4.y*sc.y;
  sc.z = g4.z * rsqrtf(v4.z + 1e-5f);  off.z = b4.z - m4.z*sc.z;
  sc.w = g4.w * rsqrtf(v4.w + 1e-5f);  off.w = b4.w - m4.w*sc.w;
#pragma unroll
  for (int i = 0; i < 4; ++i) {
    int m = m0 + 2*mq + 16*i;          // even; pair (m, m+1)
    int b = m / 156, t = m - b*156;    // t even; pair (t, t+1), same b
    if (t <= 152) {                    // u = t/2 in [0,76]
      int u = t >> 1;
      float4 o;
      o.x = fmaxf(0.f, fmaxf(acc[2*i][0], acc[2*i+1][0]) + bias.x) * sc.x + off.x;
      o.y = fmaxf(0.f, fmaxf(acc[2*i][1], acc[2*i+1][1]) + bias.y) * sc.y + off.y;
      o.z = fmaxf(0.f, fmaxf(acc[2*i][2], acc[2*i+1][2]) + bias.z) * sc.z + off.z;
      o.w = fmaxf(0.f, fmaxf(acc[2*i][3], acc[2*i+1][3]) + bias.w) * sc.w + off.w;
      *reinterpret_cast<float4*>(X + u*32768 + b*128 + 4*un) = o;
    }
  }
}

// ---- fence-free h exchange: relaxed AGENT-scope 8B atomics (sc1, bypass per-XCD L2,
// coherent at L3). Proven r11: removing the per-step fences cut persist 1628->984us. ----
__device__ __forceinline__ float2 h_load2(const float* p) {
  unsigned long long v = __hip_atomic_load((const unsigned long long*)p,
                                           __ATOMIC_RELAXED, __HIP_MEMORY_SCOPE_AGENT);
  float2 r;
  r.x = __uint_as_float((unsigned)v);
  r.y = __uint_as_float((unsigned)(v >> 32));
  return r;
}
__device__ __forceinline__ void h_store2(float* p, float a, float b) {
  unsigned long long v = (unsigned long long)__float_as_uint(a)
                       | ((unsigned long long)__float_as_uint(b) << 32);
  __hip_atomic_store((unsigned long long*)p, v,
                     __ATOMIC_RELAXED, __HIP_MEMORY_SCOPE_AGENT);
}

// ---------------- persistent LSTM v8: V6 + layer-decoupled barrier (3-parity h0) ----------------
// r11 V6 = 984us; r12/r13 reduction restructures both lost -> intra-block tail is
// hidden. v8 attacks the INTER-block coupling: barrier groups mix L0 (6 chunks) and
// L1 (8 chunks), so every step ran at max(L0,L1)+32-block skew. Now:
//  - h0 has THREE parities (s mod 3). L0 step s reads h0[s%3], writes h0[(s+1)%3];
//    L1 step s reads h0[s%3] and h1[s&1].
//  - L1 wait unchanged: all 32 slots >= s+1.
//  - L0 wait RELAXED: own 16 L0 slots >= s+1, L1 slots >= s (one-step lag).
//    Clobber proof: L0 step s+2 writes h0[(s+3)%3] == h0[s%3]; readers were step-s
//    blocks; L0 can't BEGIN step s+2 until L1 >= s+1 (L1 done reading h0[s%3]).
//    Monotone counters -> no deadlock.
//  - Effect: L0 runs up to 1 step ahead; its signals reach L1's barrier early, so
//    L1 waits only on its own 16-member skew; jitter absorbed by the slack.
// All persist internals otherwise byte-identical to measured-best V6.
__global__ __launch_bounds__(256) void k_lstm_persist(
    const float* __restrict__ X,
    const float* __restrict__ Wih0, const float* __restrict__ Whh0,
    const float* __restrict__ bih0, const float* __restrict__ bhh0,
    const float* __restrict__ Wih1, const float* __restrict__ Whh1,
    const float* __restrict__ bih1, const float* __restrict__ bhh1,
    float* __restrict__ h0buf, float* __restrict__ h1buf,
    unsigned* bar) {
  __shared__ __align__(16) float w_lds[512*64];   // [k][col], col = 4*ulocal + gate
  __shared__ __align__(16) float a_lds[4*2*16*32];// per-wave 2x [16k][32b] (dbuf)
  __shared__ __align__(16) float red[2048];       // reduction buffer (one wave's acc)

  const int blk  = blockIdx.x;
  const int g    = blk & 7;          // b-tile / barrier group
  const int role = blk >> 3;         // 0..31 (0-15 layer0, 16-31 layer1)
  const int layer = role >> 4;
  const int u0   = (role & 15) * 16;
  const int b0   = g * 32;
  const int tid  = threadIdx.x;
  const int wv   = tid >> 6;
  const int lane = tid & 63;
  const int bq   = lane >> 3;        // batches b0 + 4*bq + {0..3}
  const int rq   = lane & 7;         // cols 8*rq + {0..7}
  const int K    = layer ? 512 : 384;
  const int KW   = K >> 2;           // per-wave K range
  const int k0w  = wv * KW;
  const int NSC  = KW >> 4;          // 16-k sub-chunks per wave: 8 / 6

  // ---- one-time W staging: [k][64col], col c -> global row (c&3)*256 + u0 + (c>>2) ----
  {
    const int c = tid & 63;
    const int kq4 = (tid >> 6) << 2;
    const int row = (c & 3)*256 + u0 + (c >> 2);
    for (int kb = 0; kb < K; kb += 16) {
      const int kg = kb + kq4;
      const float* wp; int wstr, woff;
      if (layer == 0) {
        if (kg < 128) { wp = Wih0; wstr = 128; woff = kg; }
        else          { wp = Whh0; wstr = 256; woff = kg - 128; }
      } else {
        if (kg < 256) { wp = Wih1; wstr = 256; woff = kg; }
        else          { wp = Whh1; wstr = 256; woff = kg - 256; }
      }
      float4 v = *reinterpret_cast<const float4*>(wp + row*wstr + woff);
      w_lds[(kg+0)*64 + c] = v.x;
      w_lds[(kg+1)*64 + c] = v.y;
      w_lds[(kg+2)*64 + c] = v.z;
      w_lds[(kg+3)*64 + c] = v.w;
    }
  }

  // biases + persistent cell state (used by wave 0 only)
  const float* bi_p = layer ? bih1 : bih0;
  const float* bh_p = layer ? bhh1 : bhh0;
  float bsum[2][4];
#pragma unroll
  for (int uj = 0; uj < 2; ++uj) {
    const int uu = u0 + 2*rq + uj;
#pragma unroll
    for (int gt = 0; gt < 4; ++gt)
      bsum[uj][gt] = bi_p[gt*256 + uu] + bh_p[gt*256 + uu];
  }
  float c_reg[2][4] = {{0.f,0.f,0.f,0.f},{0.f,0.f,0.f,0.f}};

  float* aw = a_lds + (wv << 10);    // wave-private 1024-float region (2 halves)
  const int bl = lane & 31, jq = lane >> 5;
  unsigned* slot = bar + ((g*32 + role) << 4);
  unsigned* gbase = bar + ((g*32) << 4);

  float4 av0, av1;
#define PF_A(kcg, ss) do {                                                        \
    const int kc_ = (kcg);                                                        \
    const int pr3_ = (ss) % 3;                                                    \
    const float* ap; int astr, aoff; bool at_;                                    \
    if (layer == 0) {                                                             \
      if (kc_ < 128) { ap = X + (ss)*32768;          astr = 128; aoff = kc_;       at_ = false; } \
      else           { ap = h0buf + pr3_*65536;      astr = 256; aoff = kc_ - 128; at_ = true; }  \
    } else {                                                                      \
      if (kc_ < 256) { ap = h0buf + pr3_*65536;      astr = 256; aoff = kc_;       at_ = true; }  \
      else           { ap = h1buf + ((ss)&1)*65536;  astr = 256; aoff = kc_ - 256; at_ = true; }  \
    }                                                                             \
    const float* base_ = ap + (b0 + bl)*astr + aoff + 4*jq;                       \
    if (at_) {                                                                    \
      float2 p0 = h_load2(base_),     p1 = h_load2(base_ + 2);                    \
      float2 p2 = h_load2(base_ + 8), p3 = h_load2(base_ + 10);                   \
      av0 = make_float4(p0.x, p0.y, p1.x, p1.y);                                  \
      av1 = make_float4(p2.x, p2.y, p3.x, p3.y);                                  \
    } else {                                                                      \
      av0 = *reinterpret_cast<const float4*>(base_);                              \
      av1 = *reinterpret_cast<const float4*>(base_ + 8);                          \
    }                                                                             \
  } while (0)

  // X-sourced chunk-0 waves may prefetch across the barrier (immutable data)
  const bool pf_early = (layer == 0) && (k0w + 16 <= 128);
  if (pf_early) { PF_A(k0w, 0); }

  __syncthreads();   // w_lds ready

#pragma unroll 1
  for (int s = 0; s <= 77; ++s) {
    const bool active = layer ? (s >= 1) : (s < 77);
    if (active) {
      if (!pf_early) { PF_A(k0w, s); }   // h-sourced: after barrier observation
      float acc[4][8];
#pragma unroll
      for (int i = 0; i < 4; ++i)
#pragma unroll
        for (int j = 0; j < 8; ++j) acc[i][j] = 0.f;

#pragma unroll 1
      for (int sc = 0; sc < NSC; ++sc) {
        float* awc = aw + ((sc & 1) << 9);   // double-buffer half
        awc[(4*jq+0)*32 + bl]  = av0.x;
        awc[(4*jq+1)*32 + bl]  = av0.y;
        awc[(4*jq+2)*32 + bl]  = av0.z;
        awc[(4*jq+3)*32 + bl]  = av0.w;
        awc[(4*jq+8)*32 + bl]  = av1.x;
        awc[(4*jq+9)*32 + bl]  = av1.y;
        awc[(4*jq+10)*32 + bl] = av1.z;
        awc[(4*jq+11)*32 + bl] = av1.w;
        if (sc + 1 < NSC) { PF_A(k0w + 16*(sc+1), s); }
        const float* wk = w_lds + ((k0w + (sc << 4)) << 6);
#pragma unroll
        for (int kl = 0; kl < 16; ++kl) {
          const float4 a4  = *reinterpret_cast<const float4*>(awc + kl*32 + 4*bq);
          const float4 wA  = *reinterpret_cast<const float4*>(wk + (kl<<6) + 8*rq);
          const float4 wB  = *reinterpret_cast<const float4*>(wk + (kl<<6) + 8*rq + 4);
          acc[0][0] += a4.x*wA.x; acc[0][1] += a4.x*wA.y; acc[0][2] += a4.x*wA.z; acc[0][3] += a4.x*wA.w;
          acc[0][4] += a4.x*wB.x; acc[0][5] += a4.x*wB.y; acc[0][6] += a4.x*wB.z; acc[0][7] += a4.x*wB.w;
          acc[1][0] += a4.y*wA.x; acc[1][1] += a4.y*wA.y; acc[1][2] += a4.y*wA.z; acc[1][3] += a4.y*wA.w;
          acc[1][4] += a4.y*wB.x; acc[1][5] += a4.y*wB.y; acc[1][6] += a4.y*wB.z; acc[1][7] += a4.y*wB.w;
          acc[2][0] += a4.z*wA.x; acc[2][1] += a4.z*wA.y; acc[2][2] += a4.z*wA.z; acc[2][3] += a4.z*wA.w;
          acc[2][4] += a4.z*wB.x; acc[2][5] += a4.z*wB.y; acc[2][6] += a4.z*wB.z; acc[2][7] += a4.z*wB.w;
          acc[3][0] += a4.w*wA.x; acc[3][1] += a4.w*wA.y; acc[3][2] += a4.w*wA.z; acc[3][3] += a4.w*wA.w;
          acc[3][4] += a4.w*wB.x; acc[3][5] += a4.w*wB.y; acc[3][6] += a4.w*wB.z; acc[3][7] += a4.w*wB.w;
        }
      }

      // ---- cross-wave K reduction: w3 -> w2 -> w1 -> w0 (8KB in-place) ----
      __syncthreads();
      if (wv == 3) {
#pragma unroll
        for (int qi = 0; qi < 8; ++qi) {
          const int bi = qi >> 1, c0 = (qi & 1) << 2;
          *reinterpret_cast<float4*>(&red[((qi<<6) + lane) << 2]) =
            make_float4(acc[bi][c0], acc[bi][c0+1], acc[bi][c0+2], acc[bi][c0+3]);
        }
      }
      __syncthreads();
      if (wv == 2) {
#pragma unroll
        for (int qi = 0; qi < 8; ++qi) {
          const int bi = qi >> 1, c0 = (qi & 1) << 2;
          float4 v = *reinterpret_cast<const float4*>(&red[((qi<<6) + lane) << 2]);
          *reinterpret_cast<float4*>(&red[((qi<<6) + lane) << 2]) =
            make_float4(acc[bi][c0]+v.x, acc[bi][c0+1]+v.y, acc[bi][c0+2]+v.z, acc[bi][c0+3]+v.w);
        }
      }
      __syncthreads();
      if (wv == 1) {
#pragma unroll
        for (int qi = 0; qi < 8; ++qi) {
          const int bi = qi >> 1, c0 = (qi & 1) << 2;
          float4 v = *reinterpret_cast<const float4*>(&red[((qi<<6) + lane) << 2]);
          *reinterpret_cast<float4*>(&red[((qi<<6) + lane) << 2]) =
            make_float4(acc[bi][c0]+v.x, acc[bi][c0+1]+v.y, acc[bi][c0+2]+v.z, acc[bi][c0+3]+v.w);
        }
      }
      __syncthreads();
      if (wv == 0) {
#pragma unroll
        for (int qi = 0; qi < 8; ++qi) {
          const int bi = qi >> 1, c0 = (qi & 1) << 2;
          float4 v = *reinterpret_cast<const float4*>(&red[((qi<<6) + lane) << 2]);
          acc[bi][c0]   += v.x;
          acc[bi][c0+1] += v.y;
          acc[bi][c0+2] += v.z;
          acc[bi][c0+3] += v.w;
        }
        float* __restrict__ hw = layer ? (h1buf + ((s+1)&1)*65536)
                                       : (h0buf + ((s+1)%3)*65536);
#pragma unroll
        for (int bi = 0; bi < 4; ++bi) {
          float hv[2];
#pragma unroll
          for (int uj = 0; uj < 2; ++uj) {
            float gi = acc[bi][4*uj+0] + bsum[uj][0];
            float gf = acc[bi][4*uj+1] + bsum[uj][1];
            float gg = acc[bi][4*uj+2] + bsum[uj][2];
            float go = acc[bi][4*uj+3] + bsum[uj][3];
            float si = 1.f/(1.f + expf(-gi));
            float sf = 1.f/(1.f + expf(-gf));
            float so = 1.f/(1.f + expf(-go));
            float tg = tanhf(gg);
            float cn = sf*c_reg[uj][bi] + si*tg;
            c_reg[uj][bi] = cn;
            hv[uj] = so*tanhf(cn);
          }
          h_store2(hw + (b0 + 4*bq + bi)*256 + u0 + 2*rq, hv[0], hv[1]);
        }
        // no fence: stores are agent-scope sc1 atomics (coherent at L3); the
        // vmcnt(0) drain inside the next __syncthreads orders them before the
        // slot release below (wave0 program order).
      }
    }
    if (s == 77) break;
    __syncthreads();                // all waves done; drains wave0's h-stores
    if (tid == 0)
      __hip_atomic_store(slot, (unsigned)(s+1), __ATOMIC_RELAXED, __HIP_MEMORY_SCOPE_AGENT);
    // pre-spin prefetch of next step's chunk-0 A for X-sourced waves (race-free)
    if (pf_early && (s + 1 < 77)) { PF_A(k0w, s + 1); }
    if (wv == 0) {
      // L1: all 32 slots >= s+1. L0: own 16 >= s+1, L1's 16 >= s (one-step lag).
      const unsigned tgt = (unsigned)(s+1);
      const unsigned thr = (layer == 0 && lane >= 16) ? (unsigned)s : tgt;
      for (;;) {
        unsigned v = thr;
        if (lane < 32)
          v = __hip_atomic_load(gbase + (lane << 4), __ATOMIC_RELAXED, __HIP_MEMORY_SCOPE_AGENT);
        if (__all(v >= thr)) break;
        __builtin_amdgcn_s_sleep(2);
      }
      asm volatile("" ::: "memory");   // compiler barrier: no hoisting h-loads above spin
    }
    __syncthreads();
    if (layer == 1) {
      const int ns = s + 1;
      if (ns >= 1 && ns <= 77) PF_A(0, ns);   // h0-sourced: after barrier observation
    }
  }
#undef PF_A
}

// ---------------- FC: C = act(A @ W^T + b), M=256 ----------------
__global__ __launch_bounds__(256) void k_fc(const float* __restrict__ A,
    const float* __restrict__ W, const float* __restrict__ bias,
    float* __restrict__ Cout, int N, int K, int kshift, int dorelu) {
  __shared__ __align__(16) float sa[16*516];
  int m0 = blockIdx.y * 16;
  int n = blockIdx.x * 16 + (threadIdx.x & 15);
  int m = threadIdx.x >> 4;
  int stride = K + 4;
  for (int i = threadIdx.x; i < 16*K; i += 256) {
    int mm = i >> kshift;
    int kk = i - (mm << kshift);
    sa[mm*stride + kk] = A[(m0+mm)*K + kk];
  }
  __syncthreads();
  const float4* wr = reinterpret_cast<const float4*>(W + n*K);
  const float4* ar = reinterpret_cast<const float4*>(sa + m*stride);
  float acc = 0.f;
  int kq4 = K >> 2;
  for (int kq = 0; kq < kq4; ++kq) {
    float4 wv = wr[kq], av = ar[kq];
    acc += av.x*wv.x + av.y*wv.y + av.z*wv.z + av.w*wv.w;
  }
  acc += bias[n];
  if (dorelu) acc = fmaxf(acc, 0.f);
  Cout[(m0+m)*N + n] = acc;
}

extern "C" void kernel_launch(void* const* d_in, const int* in_sizes, int n_in,
                              void* d_out, int out_size, void* d_ws, size_t ws_size,
                              hipStream_t stream) {
  const float* x       = (const float*)d_in[0];
  const float* conv_w0 = (const float*)d_in[1];
  const float* conv_b0 = (const float*)d_in[2];
  const float* bn_g0   = (const float*)d_in[3];
  const float* bn_b0   = (const float*)d_in[4];
  const float* bn_m0   = (const float*)d_in[5];
  const float* bn_v0   = (const float*)d_in[6];
  const float* conv_w1 = (const float*)d_in[7];
  const float* conv_b1 = (const float*)d_in[8];
  const float* bn_g1   = (const float*)d_in[9];
  const float* bn_b1   = (const float*)d_in[10];
  const float* bn_m1   = (const float*)d_in[11];
  const float* bn_v1   = (const float*)d_in[12];
  const float* Wih0    = (const float*)d_in[13];
  const float* Whh0    = (const float*)d_in[14];
  const float* bih0    = (const float*)d_in[15];
  const float* bhh0    = (const float*)d_in[16];
  const float* Wih1    = (const float*)d_in[17];
  const float* Whh1    = (const float*)d_in[18];
  const float* bih1    = (const float*)d_in[19];
  const float* bhh1    = (const float*)d_in[20];
  const float* fc0_w   = (const float*)d_in[21];
  const float* fc0_b   = (const float*)d_in[22];
  const float* fc1_w   = (const float*)d_in[23];
  const float* fc1_b   = (const float*)d_in[24];
  const float* out_w   = (const float*)d_in[25];
  const float* out_b   = (const float*)d_in[26];
  float* ws = (float*)d_ws;
  float* out = (float*)d_out;

  static float h_consts[160];
  compute_consts(h_consts);
  hipMemcpyAsync(ws + OFF_CONST, h_consts, 160*sizeof(float), hipMemcpyHostToDevice, stream);
  hipMemsetAsync(ws + OFF_H0, 0, 393216*sizeof(float), stream);  // h0(3 par)+h1(2 par)+slack
  hipMemsetAsync(ws + OFF_BAR, 0, 16384, stream);   // barrier slot lines -> 0

  k_sgconv0<<<dim3(3, BATCH), 256, 0, stream>>>(x, ws + OFF_CONST, conv_w0, conv_b0,
                                                bn_g0, bn_b0, bn_m0, bn_v0, ws + OFF_Y1);
  k_conv1_gemm<<<624, 256, 0, stream>>>(ws + OFF_Y1, conv_w1, conv_b1,
                                        bn_g1, bn_b1, bn_m1, bn_v1, ws + OFF_X);
  k_lstm_persist<<<256, 256, 0, stream>>>(ws + OFF_X, Wih0, Whh0, bih0, bhh0,
                                          Wih1, Whh1, bih1, bhh1,
                                          ws + OFF_H0, ws + OFF_H1,
                                          (unsigned*)(ws + OFF_BAR));
  k_fc<<<dim3(32, 16), 256, 0, stream>>>(ws + OFF_H1, fc0_w, fc0_b, ws + OFF_Z0, 512, 256, 8, 1);
  k_fc<<<dim3(32, 16), 256, 0, stream>>>(ws + OFF_Z0, fc1_w, fc1_b, ws + OFF_Z1, 512, 512, 9, 1);
  k_fc<<<dim3(16, 16), 256, 0, stream>>>(ws + OFF_Z1, out_w, out_b, out, 256, 512, 9, 0);
}